// Round 1
// baseline (490.257 us; speedup 1.0000x reference)
//
#include <hip/hip_runtime.h>
#include <math.h>

#define BATCH 256
#define INDIM 256
#define HDIM  512
#define BH    (BATCH * HDIM)

__device__ __forceinline__ float sigmoidf_(float v) {
    return 1.0f / (1.0f + expf(-v));
}

// ---------------------------------------------------------------------------
// Kernel 1: gates GEMM.  out[m, n] = sum_k Wall[m,k] * x[n,k]
// M = 6*512 = 3072 (gate-major rows), N = 256 (batch), K = 256.
// Tiles: 64x64, K-chunks of 64. 256 threads, 4x4 microtile per thread.
// Fused epilogue: +bias, activation, store as gates[g][b][h].
// ---------------------------------------------------------------------------
__global__ __launch_bounds__(256) void gates_kernel(
    const float* __restrict__ x,
    const float* __restrict__ Wq, const float* __restrict__ bq,
    const float* __restrict__ Wk, const float* __restrict__ bk,
    const float* __restrict__ Wv, const float* __restrict__ bv,
    const float* __restrict__ Wi, const float* __restrict__ bi,
    const float* __restrict__ Wf, const float* __restrict__ bf,
    const float* __restrict__ Wo, const float* __restrict__ bo,
    float* __restrict__ gates)
{
    __shared__ float Wt[64][65];
    __shared__ float Xt[64][65];

    const int m0 = blockIdx.x * 64;           // gate-row tile base (0..3071)
    const int n0 = blockIdx.y * 64;           // batch tile base
    const int t  = threadIdx.x;

    const int g  = m0 >> 9;                   // gate index, block-uniform
    const int h0 = m0 & 511;

    const float* W; const float* bias;
    switch (g) {
        case 0: W = Wq; bias = bq; break;
        case 1: W = Wk; bias = bk; break;
        case 2: W = Wv; bias = bv; break;
        case 3: W = Wi; bias = bi; break;
        case 4: W = Wf; bias = bf; break;
        default: W = Wo; bias = bo; break;
    }
    const float* Wg = W + (size_t)h0 * INDIM;

    const int tx = t & 15;                    // n microtile group
    const int ty = t >> 4;                    // m microtile group

    float acc[4][4] = {};

    for (int k0 = 0; k0 < INDIM; k0 += 64) {
        const int kk4 = (t & 15) * 4;
        const int row = t >> 4;               // 0..15
        #pragma unroll
        for (int rr = 0; rr < 4; rr++) {
            const int mr = row + rr * 16;
            const float4 w = *(const float4*)(Wg + mr * INDIM + k0 + kk4);
            Wt[mr][kk4 + 0] = w.x; Wt[mr][kk4 + 1] = w.y;
            Wt[mr][kk4 + 2] = w.z; Wt[mr][kk4 + 3] = w.w;
            const float4 xv = *(const float4*)(x + (n0 + mr) * INDIM + k0 + kk4);
            Xt[mr][kk4 + 0] = xv.x; Xt[mr][kk4 + 1] = xv.y;
            Xt[mr][kk4 + 2] = xv.z; Xt[mr][kk4 + 3] = xv.w;
        }
        __syncthreads();
        #pragma unroll 8
        for (int kk = 0; kk < 64; kk++) {
            float a[4], bb[4];
            #pragma unroll
            for (int i2 = 0; i2 < 4; i2++) a[i2] = Wt[ty * 4 + i2][kk];
            #pragma unroll
            for (int j = 0; j < 4; j++) bb[j] = Xt[tx * 4 + j][kk];
            #pragma unroll
            for (int i2 = 0; i2 < 4; i2++)
                #pragma unroll
                for (int j = 0; j < 4; j++)
                    acc[i2][j] += a[i2] * bb[j];
        }
        __syncthreads();
    }

    const float inv_sqrt_h = 0.044194173824159216f;   // 1/sqrt(512)
    #pragma unroll
    for (int i2 = 0; i2 < 4; i2++) {
        const int h = h0 + ty * 4 + i2;
        const float bv_ = bias[h];
        #pragma unroll
        for (int j = 0; j < 4; j++) {
            const int n = n0 + tx * 4 + j;
            float val = acc[i2][j] + bv_;
            if (g == 1)      val *= inv_sqrt_h;       // k (scaled)
            else if (g == 3) val = expf(val);          // i
            else if (g >= 4) val = sigmoidf_(val);     // f, o
            gates[(size_t)g * BH + (size_t)n * HDIM + h] = val;
        }
    }
}

// ---------------------------------------------------------------------------
// Kernel 2: n_t = f*n_prev + i*k ; denom[b] = max(|dot(n_t, q)|, 1)
// One block per batch element.
// ---------------------------------------------------------------------------
__global__ __launch_bounds__(256) void nt_denom_kernel(
    const float* __restrict__ gates,
    const float* __restrict__ n_prev,
    float* __restrict__ n_out,
    float* __restrict__ denom)
{
    const int b = blockIdx.x;
    const int t = threadIdx.x;
    const int lane = t & 63;
    const int wave = t >> 6;

    const float* qb = gates + 0 * (size_t)BH + (size_t)b * HDIM;
    const float* kb = gates + 1 * (size_t)BH + (size_t)b * HDIM;
    const float* ib = gates + 3 * (size_t)BH + (size_t)b * HDIM;
    const float* fb = gates + 4 * (size_t)BH + (size_t)b * HDIM;
    const float* npv = n_prev + (size_t)b * HDIM;

    float partial = 0.0f;
    for (int h = t; h < HDIM; h += 256) {
        const float nt = fb[h] * npv[h] + ib[h] * kb[h];
        n_out[(size_t)b * HDIM + h] = nt;
        partial += nt * qb[h];
    }
    #pragma unroll
    for (int off = 32; off > 0; off >>= 1)
        partial += __shfl_down(partial, off);

    __shared__ float red[4];
    if (lane == 0) red[wave] = partial;
    __syncthreads();
    if (t == 0) {
        const float s = red[0] + red[1] + red[2] + red[3];
        denom[b] = fmaxf(fabsf(s), 1.0f);
    }
}

// ---------------------------------------------------------------------------
// Kernel 3: the 512 MB pass.
// C_t[b,r,c] = f[b,c]*C_prev[b,r,c] + v[b,r]*(i[b,c]*k[b,c])
// fused: h_t[b,r] = o[b,r] * (sum_c C_t[b,r,c]*q[b,c]) / denom[b]
// Grid: B * (H/32) blocks, 256 threads (4 waves), each wave owns 8 rows.
// Per-c gate vectors live in registers (same c-offsets for every row).
// ---------------------------------------------------------------------------
__global__ __launch_bounds__(256) void cell_kernel(
    const float* __restrict__ C_prev,
    const float* __restrict__ gates,
    const float* __restrict__ denom_arr,
    float* __restrict__ C_out,
    float* __restrict__ h_out)
{
    const int blk    = blockIdx.x;
    const int b      = blk >> 4;        // /16 row-chunks per batch
    const int rchunk = blk & 15;
    const int wave   = threadIdx.x >> 6;
    const int lane   = threadIdx.x & 63;

    const float* qb = gates + 0 * (size_t)BH + (size_t)b * HDIM;
    const float* kb = gates + 1 * (size_t)BH + (size_t)b * HDIM;
    const float* vb = gates + 2 * (size_t)BH + (size_t)b * HDIM;
    const float* ib = gates + 3 * (size_t)BH + (size_t)b * HDIM;
    const float* fb = gates + 4 * (size_t)BH + (size_t)b * HDIM;
    const float* ob = gates + 5 * (size_t)BH + (size_t)b * HDIM;

    const int c0 = lane * 4;            // first float4 (c in [0,256))
    // c1 = c0 + 256                    // second float4

    const float4 f0 = *(const float4*)(fb + c0);
    const float4 f1 = *(const float4*)(fb + 256 + c0);
    const float4 q0 = *(const float4*)(qb + c0);
    const float4 q1 = *(const float4*)(qb + 256 + c0);
    const float4 i0 = *(const float4*)(ib + c0);
    const float4 i1 = *(const float4*)(ib + 256 + c0);
    const float4 k0 = *(const float4*)(kb + c0);
    const float4 k1 = *(const float4*)(kb + 256 + c0);
    float4 a0, a1;                      // i*k per c
    a0.x = i0.x * k0.x; a0.y = i0.y * k0.y; a0.z = i0.z * k0.z; a0.w = i0.w * k0.w;
    a1.x = i1.x * k1.x; a1.y = i1.y * k1.y; a1.z = i1.z * k1.z; a1.w = i1.w * k1.w;

    const float dinv = 1.0f / denom_arr[b];

    const size_t base = (size_t)b * HDIM * HDIM;
    const int r0 = rchunk * 32 + wave * 8;

    #pragma unroll
    for (int rr = 0; rr < 8; rr++) {
        const int r = r0 + rr;
        const float vr = vb[r];
        const float* cp = C_prev + base + (size_t)r * HDIM;
        float*       co = C_out  + base + (size_t)r * HDIM;

        const float4 c0v = *(const float4*)(cp + c0);
        const float4 c1v = *(const float4*)(cp + 256 + c0);

        float4 t0, t1;
        t0.x = f0.x * c0v.x + vr * a0.x;
        t0.y = f0.y * c0v.y + vr * a0.y;
        t0.z = f0.z * c0v.z + vr * a0.z;
        t0.w = f0.w * c0v.w + vr * a0.w;
        t1.x = f1.x * c1v.x + vr * a1.x;
        t1.y = f1.y * c1v.y + vr * a1.y;
        t1.z = f1.z * c1v.z + vr * a1.z;
        t1.w = f1.w * c1v.w + vr * a1.w;

        *(float4*)(co + c0)       = t0;
        *(float4*)(co + 256 + c0) = t1;

        float dot = t0.x * q0.x + t0.y * q0.y + t0.z * q0.z + t0.w * q0.w
                  + t1.x * q1.x + t1.y * q1.y + t1.z * q1.z + t1.w * q1.w;
        #pragma unroll
        for (int off = 32; off > 0; off >>= 1)
            dot += __shfl_down(dot, off);

        if (lane == 0)
            h_out[(size_t)b * HDIM + r] = ob[r] * dot * dinv;
    }
}

// ---------------------------------------------------------------------------
extern "C" void kernel_launch(void* const* d_in, const int* in_sizes, int n_in,
                              void* d_out, int out_size, void* d_ws, size_t ws_size,
                              hipStream_t stream) {
    const float* x      = (const float*)d_in[0];
    const float* C_prev = (const float*)d_in[1];
    const float* n_prev = (const float*)d_in[2];
    const float* Wq = (const float*)d_in[3];  const float* bq = (const float*)d_in[4];
    const float* Wk = (const float*)d_in[5];  const float* bk = (const float*)d_in[6];
    const float* Wv = (const float*)d_in[7];  const float* bv = (const float*)d_in[8];
    const float* Wi = (const float*)d_in[9];  const float* bi = (const float*)d_in[10];
    const float* Wf = (const float*)d_in[11]; const float* bf = (const float*)d_in[12];
    const float* Wo = (const float*)d_in[13]; const float* bo = (const float*)d_in[14];

    float* out   = (float*)d_out;
    float* C_out = out;                                    // [B,H,H]
    float* n_out = out + (size_t)BATCH * HDIM * HDIM;      // [B,H]
    float* h_out = n_out + (size_t)BATCH * HDIM;           // [B,H]

    float* gates = (float*)d_ws;                           // 6*B*H floats
    float* denom = gates + 6 * (size_t)BH;                 // B floats

    dim3 gridA(3072 / 64, BATCH / 64);                     // 48 x 4
    gates_kernel<<<gridA, 256, 0, stream>>>(x, Wq, bq, Wk, bk, Wv, bv,
                                            Wi, bi, Wf, bf, Wo, bo, gates);
    nt_denom_kernel<<<BATCH, 256, 0, stream>>>(gates, n_prev, n_out, denom);
    cell_kernel<<<BATCH * (HDIM / 32), 256, 0, stream>>>(C_prev, gates, denom,
                                                         C_out, h_out);
}